// Round 6
// baseline (376.314 us; speedup 1.0000x reference)
//
#include <hip/hip_runtime.h>
#include <stdint.h>

#define DI __device__ __forceinline__

typedef __attribute__((ext_vector_type(8))) short bf16x8;
typedef __attribute__((ext_vector_type(4))) float f32x4;
typedef __attribute__((ext_vector_type(8))) unsigned short u16x8;

static constexpr int BATCH = 4, SEQ = 2048, DIM = 1024, NH = 16, HDIM = 64, DOUT = 256;
static constexpr int MROWS = BATCH * SEQ;  // 8192

DI unsigned short f2b(float f) {
  union { float f; unsigned u; } v; v.f = f;
  unsigned u = v.u + 0x7FFFu + ((v.u >> 16) & 1u);
  return (unsigned short)(u >> 16);
}

typedef const __attribute__((address_space(1))) unsigned int* gp1;
typedef __attribute__((address_space(3))) unsigned int* lp3;
DI void gload16(const void* g, void* l) {
  __builtin_amdgcn_global_load_lds((gp1)g, (lp3)l, 16, 0, 0);
}

// ---------------- f32 -> bf16 convert (8 elems/thread) ----------------
__global__ void k_cvt(const float* __restrict__ s, unsigned short* __restrict__ d, int n8) {
  int i = blockIdx.x * 256 + threadIdx.x;
  if (i >= n8) return;
  const float4* sp = reinterpret_cast<const float4*>(s) + (size_t)i * 2;
  float4 a = sp[0], b = sp[1];
  u16x8 r;
  r[0] = f2b(a.x); r[1] = f2b(a.y); r[2] = f2b(a.z); r[3] = f2b(a.w);
  r[4] = f2b(b.x); r[5] = f2b(b.y); r[6] = f2b(b.z); r[7] = f2b(b.w);
  *reinterpret_cast<u16x8*>(d + (size_t)i * 8) = r;
}

// ---------------- f32 [R][C] -> bf16 [C][R] transpose-convert ----------------
__global__ void k_tcvt(const float* __restrict__ s, unsigned short* __restrict__ d, int R, int C) {
  __shared__ float t[32][33];
  int c0 = blockIdx.x * 32, r0 = blockIdx.y * 32;
  int tx = threadIdx.x, ty = threadIdx.y;  // block (32,8)
#pragma unroll
  for (int j = 0; j < 32; j += 8)
    t[ty + j][tx] = s[(size_t)(r0 + ty + j) * C + c0 + tx];
  __syncthreads();
#pragma unroll
  for (int j = 0; j < 32; j += 8)
    d[(size_t)(c0 + ty + j) * R + r0 + tx] = f2b(t[tx][ty + j]);
}

// ---------------- bf16 GEMM: A[M,K] x Bt[N,K]^T, 128x128 tile, BK=32 ----------------
// MODE 0: out bf16 [B,H,S,HD]   (n = h*64+hd, m = b*2048+s), v = (acc+bias)*scale
// MODE 1: out bf16 [B,H,HD,S]   (V transposed per head)
// MODE 2: out f32  [M,N] row-major
template <int MODE>
__global__ __launch_bounds__(256, 2) void k_gemm(
    const unsigned short* __restrict__ A, const unsigned short* __restrict__ Bt,
    const float* __restrict__ bias, void* __restrict__ out, int K, int N, float scale) {
  __shared__ unsigned short Al[128 * 32];
  __shared__ unsigned short Bl[128 * 32];
  const int tid = threadIdx.x, wid = tid >> 6, lane = tid & 63;
  const int m0 = blockIdx.x * 128, n0 = blockIdx.y * 128;
  const int wr = wid >> 1, wc = wid & 1;
  const int g = lane >> 4, r16 = lane & 15;

  f32x4 acc[4][4];
#pragma unroll
  for (int i = 0; i < 4; ++i)
#pragma unroll
    for (int j = 0; j < 4; ++j) acc[i][j] = f32x4{0.f, 0.f, 0.f, 0.f};

  for (int kk = 0; kk < K; kk += 32) {
#pragma unroll
    for (int is = 0; is < 2; ++is) {
      int slot = (is * 4 + wid) * 64 + lane;
      int row = slot >> 2, ch = slot & 3;
      gload16(A + (size_t)(m0 + row) * K + kk + ch * 8, &Al[(is * 4 + wid) * 64 * 8]);
    }
#pragma unroll
    for (int is = 0; is < 2; ++is) {
      int slot = (is * 4 + wid) * 64 + lane;
      int row = slot >> 2, ch = slot & 3;
      gload16(Bt + (size_t)(n0 + row) * K + kk + ch * 8, &Bl[(is * 4 + wid) * 64 * 8]);
    }
    __syncthreads();
    bf16x8 af[4], bfv[4];
#pragma unroll
    for (int i = 0; i < 4; ++i)
      af[i] = *reinterpret_cast<const bf16x8*>(&Al[(wr * 64 + i * 16 + r16) * 32 + g * 8]);
#pragma unroll
    for (int j = 0; j < 4; ++j)
      bfv[j] = *reinterpret_cast<const bf16x8*>(&Bl[(wc * 64 + j * 16 + r16) * 32 + g * 8]);
#pragma unroll
    for (int i = 0; i < 4; ++i)
#pragma unroll
      for (int j = 0; j < 4; ++j)
        acc[i][j] = __builtin_amdgcn_mfma_f32_16x16x32_bf16(af[i], bfv[j], acc[i][j], 0, 0, 0);
    __syncthreads();
  }

  const int rr = g * 4;
#pragma unroll
  for (int i = 0; i < 4; ++i) {
#pragma unroll
    for (int j = 0; j < 4; ++j) {
#pragma unroll
      for (int q = 0; q < 4; ++q) {
        int mrow = m0 + wr * 64 + i * 16 + rr + q;
        int ncol = n0 + wc * 64 + j * 16 + r16;
        float v = (acc[i][j][q] + bias[ncol]) * scale;
        if (MODE == 0) {
          int b_ = mrow >> 11, s_ = mrow & 2047;
          int h_ = ncol >> 6, hd = ncol & 63;
          ((unsigned short*)out)[(((size_t)(b_ * NH + h_) * SEQ + s_) << 6) + hd] = f2b(v);
        } else if (MODE == 1) {
          int b_ = mrow >> 11, s_ = mrow & 2047;
          int h_ = ncol >> 6, hd = ncol & 63;
          ((unsigned short*)out)[(((size_t)(b_ * NH + h_) * HDIM + hd) << 11) + s_] = f2b(v);
        } else {
          ((float*)out)[(size_t)mrow * N + ncol] = v;
        }
      }
    }
  }
}

// ---------------- flash attention with "+1" sink softmax ----------------
// Qh,Kh: bf16 [B,H,S,HD] (Q pre-scaled by 1/8); Vt: bf16 [B,H,HD,S]
// X out: bf16 [B,S,D].  grid (S/128, B*H), 256 threads (4 waves x 32 q-rows).
// Round-0 softmax numerics (verified absmax 2.44e-4) + double-buffered K/V
// staging only: STAGE(t+1) issued right after B1(t) so loads overlap
// QK^T+softmax of tile t. Math is bit-identical to the passing round-2 run.
__global__ __launch_bounds__(256, 2) void k_attn(
    const unsigned short* __restrict__ Qh, const unsigned short* __restrict__ Kh,
    const unsigned short* __restrict__ Vt, unsigned short* __restrict__ X) {
  __shared__ unsigned short Kl[2][64 * 64];  // [kv][hd], chunk-swizzled
  __shared__ unsigned short Vl[2][64 * 64];  // [hd][kv], chunk-swizzled
  __shared__ unsigned short Pl[128 * 64];    // [q][kv],  chunk-swizzled (wave-private rows)

  const int tid = threadIdx.x, wid = tid >> 6, lane = tid & 63;
  const int g = lane >> 4, r16 = lane & 15;
  const int bh = blockIdx.y, b_ = bh >> 4, h_ = bh & 15;
  const int q0 = blockIdx.x * 128;
  const unsigned short* Qp = Qh + ((size_t)bh * SEQ + q0) * HDIM;
  const unsigned short* Kp = Kh + (size_t)bh * SEQ * HDIM;
  const unsigned short* Vp = Vt + (size_t)bh * HDIM * SEQ;
  const int qw = wid * 32;

  // Q fragments for this wave's 32 rows (A-operand: row = lane&15, k = g*8..)
  bf16x8 qf[2][2];
#pragma unroll
  for (int fr = 0; fr < 2; ++fr)
#pragma unroll
    for (int ks = 0; ks < 2; ++ks)
      qf[fr][ks] = *reinterpret_cast<const bf16x8*>(
          Qp + (size_t)(qw + fr * 16 + r16) * HDIM + ks * 32 + g * 8);

  // staging source/dest offsets (swizzled source chunks; LDS dest wave-linear)
  const int slot0 = wid * 64 + lane, slot1 = (4 + wid) * 64 + lane;
  const int sr0 = slot0 >> 3, sc0 = (slot0 & 7) ^ (sr0 & 7);
  const int sr1 = slot1 >> 3, sc1 = (slot1 & 7) ^ (sr1 & 7);
  const unsigned short* Ks0 = Kp + (size_t)sr0 * HDIM + sc0 * 8;
  const unsigned short* Ks1 = Kp + (size_t)sr1 * HDIM + sc1 * 8;
  const unsigned short* Vs0 = Vp + (size_t)sr0 * SEQ + sc0 * 8;
  const unsigned short* Vs1 = Vp + (size_t)sr1 * SEQ + sc1 * 8;
  const int ld0 = wid * 512, ld1 = (4 + wid) * 512;

  float m_[2][4], l_[2][4];
  f32x4 o[2][4];
#pragma unroll
  for (int fr = 0; fr < 2; ++fr) {
#pragma unroll
    for (int q = 0; q < 4; ++q) { m_[fr][q] = 0.f; l_[fr][q] = 1.f; }  // sink: logit 0
#pragma unroll
    for (int hf = 0; hf < 4; ++hf) o[fr][hf] = f32x4{0.f, 0.f, 0.f, 0.f};
  }

  // prologue: stage tile 0 into buffer 0
  gload16(Ks0, &Kl[0][ld0]);
  gload16(Ks1, &Kl[0][ld1]);
  gload16(Vs0, &Vl[0][ld0]);
  gload16(Vs1, &Vl[0][ld1]);

  int cur = 0;
  for (int t = 0; t < SEQ / 64; ++t) {
    __syncthreads();  // B1: drains vmcnt -> tile t visible; separates prev PV reads from next STAGE
    if (t + 1 < SEQ / 64) {
      const int kv1 = (t + 1) * 64;
      gload16(Ks0 + (size_t)kv1 * HDIM, &Kl[cur ^ 1][ld0]);
      gload16(Ks1 + (size_t)kv1 * HDIM, &Kl[cur ^ 1][ld1]);
      gload16(Vs0 + kv1, &Vl[cur ^ 1][ld0]);
      gload16(Vs1 + kv1, &Vl[cur ^ 1][ld1]);
    }

    // S = Q K^T  (S rows = q, cols = kv)
    f32x4 s_[2][4];
#pragma unroll
    for (int fr = 0; fr < 2; ++fr)
#pragma unroll
      for (int cf = 0; cf < 4; ++cf) s_[fr][cf] = f32x4{0.f, 0.f, 0.f, 0.f};
#pragma unroll
    for (int cf = 0; cf < 4; ++cf) {
      int krow = cf * 16 + r16;
#pragma unroll
      for (int ks = 0; ks < 2; ++ks) {
        bf16x8 kf = *reinterpret_cast<const bf16x8*>(
            &Kl[cur][krow * 64 + (((ks * 4 + g) ^ (krow & 7)) << 3)]);
#pragma unroll
        for (int fr = 0; fr < 2; ++fr)
          s_[fr][cf] = __builtin_amdgcn_mfma_f32_16x16x32_bf16(qf[fr][ks], kf, s_[fr][cf], 0, 0, 0);
      }
    }

    // online softmax with sink (round-0 numerics: always rescale, P <= 1)
#pragma unroll
    for (int fr = 0; fr < 2; ++fr) {
#pragma unroll
      for (int q = 0; q < 4; ++q) {
        float mx = fmaxf(fmaxf(s_[fr][0][q], s_[fr][1][q]), fmaxf(s_[fr][2][q], s_[fr][3][q]));
#pragma unroll
        for (int d_ = 1; d_ < 16; d_ <<= 1) mx = fmaxf(mx, __shfl_xor(mx, d_, 64));
        float mn = fmaxf(m_[fr][q], mx);
        float sc = __expf(m_[fr][q] - mn);
        float p0 = __expf(s_[fr][0][q] - mn);
        float p1 = __expf(s_[fr][1][q] - mn);
        float p2 = __expf(s_[fr][2][q] - mn);
        float p3 = __expf(s_[fr][3][q] - mn);
        float rs = p0 + p1 + p2 + p3;
#pragma unroll
        for (int d_ = 1; d_ < 16; d_ <<= 1) rs += __shfl_xor(rs, d_, 64);
        l_[fr][q] = l_[fr][q] * sc + rs;
        m_[fr][q] = mn;
#pragma unroll
        for (int hf = 0; hf < 4; ++hf) o[fr][hf][q] *= sc;
        int prow = qw + fr * 16 + g * 4 + q;
        int base = prow * 64, swz = prow & 7;
        int lo = r16 >> 3, el = r16 & 7;
        Pl[base + (((0 + lo) ^ swz) << 3) + el] = f2b(p0);
        Pl[base + (((2 + lo) ^ swz) << 3) + el] = f2b(p1);
        Pl[base + (((4 + lo) ^ swz) << 3) + el] = f2b(p2);
        Pl[base + (((6 + lo) ^ swz) << 3) + el] = f2b(p3);
      }
    }
    __syncthreads();  // B2: Pl visible

    // O += P V   (A = P rows q, B = V cols hd from Vt rows)
#pragma unroll
    for (int ks = 0; ks < 2; ++ks) {
      bf16x8 pf[2];
#pragma unroll
      for (int fr = 0; fr < 2; ++fr) {
        int prow = qw + fr * 16 + r16;
        pf[fr] = *reinterpret_cast<const bf16x8*>(
            &Pl[prow * 64 + (((ks * 4 + g) ^ (prow & 7)) << 3)]);
      }
#pragma unroll
      for (int hf = 0; hf < 4; ++hf) {
        int vrow = hf * 16 + r16;
        bf16x8 vf = *reinterpret_cast<const bf16x8*>(
            &Vl[cur][vrow * 64 + (((ks * 4 + g) ^ (vrow & 7)) << 3)]);
#pragma unroll
        for (int fr = 0; fr < 2; ++fr)
          o[fr][hf] = __builtin_amdgcn_mfma_f32_16x16x32_bf16(pf[fr], vf, o[fr][hf], 0, 0, 0);
      }
    }
    cur ^= 1;
  }

  // epilogue: O /= l, write X[b][s][h*64+hd]
#pragma unroll
  for (int fr = 0; fr < 2; ++fr) {
#pragma unroll
    for (int q = 0; q < 4; ++q) {
      float inv = 1.0f / l_[fr][q];
      int row = q0 + qw + fr * 16 + g * 4 + q;
      unsigned short* xp = X + (size_t)(b_ * SEQ + row) * DIM + h_ * 64;
#pragma unroll
      for (int hf = 0; hf < 4; ++hf) xp[hf * 16 + r16] = f2b(o[fr][hf][q] * inv);
    }
  }
}

extern "C" void kernel_launch(void* const* d_in, const int* in_sizes, int n_in,
                              void* d_out, int out_size, void* d_ws, size_t ws_size,
                              hipStream_t stream) {
  const float* q  = (const float*)d_in[0];
  const float* k  = (const float*)d_in[1];
  const float* v  = (const float*)d_in[2];
  const float* Wq = (const float*)d_in[3];
  const float* bq = (const float*)d_in[4];
  const float* Wk = (const float*)d_in[5];
  const float* bk = (const float*)d_in[6];
  const float* Wv = (const float*)d_in[7];
  const float* bv = (const float*)d_in[8];
  const float* Wf = (const float*)d_in[9];
  const float* bf = (const float*)d_in[10];

  char* ws = (char*)d_ws;
  unsigned short* Abuf = (unsigned short*)ws;                              // 8192*1024 bf16 (also attn X)
  unsigned short* Wt   = (unsigned short*)(ws + (size_t)16777216);         // up to 1024*1024 bf16
  unsigned short* Qh   = (unsigned short*)(ws + (size_t)16777216 + 2097152);
  unsigned short* Kh   = Qh + (size_t)MROWS * DIM;
  unsigned short* Vtb  = Kh + (size_t)MROWS * DIM;

  dim3 cvtg(4096), b256(256);
  dim3 tb(32, 8);
  dim3 gemmg(64, 8);
  dim3 attng(16, 64);
  dim3 fing(64, 2);

  const int n8 = MROWS * DIM / 8;

  // Q path
  k_cvt<<<cvtg, b256, 0, stream>>>(q, Abuf, n8);
  k_tcvt<<<dim3(32, 32), tb, 0, stream>>>(Wq, Wt, DIM, DIM);
  k_gemm<0><<<gemmg, b256, 0, stream>>>(Abuf, Wt, bq, (void*)Qh, DIM, DIM, 0.125f);
  // K path
  k_cvt<<<cvtg, b256, 0, stream>>>(k, Abuf, n8);
  k_tcvt<<<dim3(32, 32), tb, 0, stream>>>(Wk, Wt, DIM, DIM);
  k_gemm<0><<<gemmg, b256, 0, stream>>>(Abuf, Wt, bk, (void*)Kh, DIM, DIM, 1.0f);
  // V path (stored transposed per head)
  k_cvt<<<cvtg, b256, 0, stream>>>(v, Abuf, n8);
  k_tcvt<<<dim3(32, 32), tb, 0, stream>>>(Wv, Wt, DIM, DIM);
  k_gemm<1><<<gemmg, b256, 0, stream>>>(Abuf, Wt, bv, (void*)Vtb, DIM, DIM, 1.0f);
  // attention -> X (reuse Abuf)
  k_attn<<<attng, b256, 0, stream>>>(Qh, Kh, Vtb, Abuf);
  // final projection -> f32 out
  k_tcvt<<<dim3(8, 32), tb, 0, stream>>>(Wf, Wt, DIM, DOUT);
  k_gemm<2><<<fing, b256, 0, stream>>>(Abuf, Wt, bf, d_out, DIM, DOUT, 1.0f);
}

// Round 7
// 251.843 us; speedup vs baseline: 1.4942x; 1.4942x over previous
//
#include <hip/hip_runtime.h>
#include <stdint.h>

#define DI __device__ __forceinline__

typedef __attribute__((ext_vector_type(8))) short bf16x8;
typedef __attribute__((ext_vector_type(4))) float f32x4;
typedef __attribute__((ext_vector_type(8))) unsigned short u16x8;

static constexpr int BATCH = 4, SEQ = 2048, DIM = 1024, NH = 16, HDIM = 64, DOUT = 256;
static constexpr int MROWS = BATCH * SEQ;  // 8192

DI unsigned short f2b(float f) {
  union { float f; unsigned u; } v; v.f = f;
  unsigned u = v.u + 0x7FFFu + ((v.u >> 16) & 1u);
  return (unsigned short)(u >> 16);
}

DI float ex2(float x) {  // 2^x, single v_exp_f32
#if __has_builtin(__builtin_amdgcn_exp2f)
  return __builtin_amdgcn_exp2f(x);
#else
  float r; asm("v_exp_f32 %0, %1" : "=v"(r) : "v"(x)); return r;
#endif
}

typedef const __attribute__((address_space(1))) unsigned int* gp1;
typedef __attribute__((address_space(3))) unsigned int* lp3;
DI void gload16(const void* g, void* l) {
  __builtin_amdgcn_global_load_lds((gp1)g, (lp3)l, 16, 0, 0);
}

// ---------------- f32 -> bf16 convert (8 elems/thread) ----------------
__global__ void k_cvt(const float* __restrict__ s, unsigned short* __restrict__ d, int n8) {
  int i = blockIdx.x * 256 + threadIdx.x;
  if (i >= n8) return;
  const float4* sp = reinterpret_cast<const float4*>(s) + (size_t)i * 2;
  float4 a = sp[0], b = sp[1];
  u16x8 r;
  r[0] = f2b(a.x); r[1] = f2b(a.y); r[2] = f2b(a.z); r[3] = f2b(a.w);
  r[4] = f2b(b.x); r[5] = f2b(b.y); r[6] = f2b(b.z); r[7] = f2b(b.w);
  *reinterpret_cast<u16x8*>(d + (size_t)i * 8) = r;
}

// ---------------- f32 [R][C] -> bf16 [C][R] transpose-convert ----------------
__global__ void k_tcvt(const float* __restrict__ s, unsigned short* __restrict__ d, int R, int C) {
  __shared__ float t[32][33];
  int c0 = blockIdx.x * 32, r0 = blockIdx.y * 32;
  int tx = threadIdx.x, ty = threadIdx.y;  // block (32,8)
#pragma unroll
  for (int j = 0; j < 32; j += 8)
    t[ty + j][tx] = s[(size_t)(r0 + ty + j) * C + c0 + tx];
  __syncthreads();
#pragma unroll
  for (int j = 0; j < 32; j += 8)
    d[(size_t)(c0 + ty + j) * R + r0 + tx] = f2b(t[tx][ty + j]);
}

// ---------------- bf16 GEMM: A[M,K] x Bt[N,K]^T, 128x128 tile, BK=32 ----------------
// MODE 0: out bf16 [B,H,S,HD]   (n = h*64+hd, m = b*2048+s), v = (acc+bias)*scale
// MODE 1: out bf16 [B,H,HD,S]   (V transposed per head)
// MODE 2: out f32  [M,N] row-major
template <int MODE>
__global__ __launch_bounds__(256, 2) void k_gemm(
    const unsigned short* __restrict__ A, const unsigned short* __restrict__ Bt,
    const float* __restrict__ bias, void* __restrict__ out, int K, int N, float scale) {
  __shared__ unsigned short Al[128 * 32];
  __shared__ unsigned short Bl[128 * 32];
  const int tid = threadIdx.x, wid = tid >> 6, lane = tid & 63;
  const int m0 = blockIdx.x * 128, n0 = blockIdx.y * 128;
  const int wr = wid >> 1, wc = wid & 1;
  const int g = lane >> 4, r16 = lane & 15;

  f32x4 acc[4][4];
#pragma unroll
  for (int i = 0; i < 4; ++i)
#pragma unroll
    for (int j = 0; j < 4; ++j) acc[i][j] = f32x4{0.f, 0.f, 0.f, 0.f};

  for (int kk = 0; kk < K; kk += 32) {
#pragma unroll
    for (int is = 0; is < 2; ++is) {
      int slot = (is * 4 + wid) * 64 + lane;
      int row = slot >> 2, ch = slot & 3;
      gload16(A + (size_t)(m0 + row) * K + kk + ch * 8, &Al[(is * 4 + wid) * 64 * 8]);
    }
#pragma unroll
    for (int is = 0; is < 2; ++is) {
      int slot = (is * 4 + wid) * 64 + lane;
      int row = slot >> 2, ch = slot & 3;
      gload16(Bt + (size_t)(n0 + row) * K + kk + ch * 8, &Bl[(is * 4 + wid) * 64 * 8]);
    }
    __syncthreads();
    bf16x8 af[4], bfv[4];
#pragma unroll
    for (int i = 0; i < 4; ++i)
      af[i] = *reinterpret_cast<const bf16x8*>(&Al[(wr * 64 + i * 16 + r16) * 32 + g * 8]);
#pragma unroll
    for (int j = 0; j < 4; ++j)
      bfv[j] = *reinterpret_cast<const bf16x8*>(&Bl[(wc * 64 + j * 16 + r16) * 32 + g * 8]);
#pragma unroll
    for (int i = 0; i < 4; ++i)
#pragma unroll
      for (int j = 0; j < 4; ++j)
        acc[i][j] = __builtin_amdgcn_mfma_f32_16x16x32_bf16(af[i], bfv[j], acc[i][j], 0, 0, 0);
    __syncthreads();
  }

  const int rr = g * 4;
#pragma unroll
  for (int i = 0; i < 4; ++i) {
#pragma unroll
    for (int j = 0; j < 4; ++j) {
#pragma unroll
      for (int q = 0; q < 4; ++q) {
        int mrow = m0 + wr * 64 + i * 16 + rr + q;
        int ncol = n0 + wc * 64 + j * 16 + r16;
        float v = (acc[i][j][q] + bias[ncol]) * scale;
        if (MODE == 0) {
          int b_ = mrow >> 11, s_ = mrow & 2047;
          int h_ = ncol >> 6, hd = ncol & 63;
          ((unsigned short*)out)[(((size_t)(b_ * NH + h_) * SEQ + s_) << 6) + hd] = f2b(v);
        } else if (MODE == 1) {
          int b_ = mrow >> 11, s_ = mrow & 2047;
          int h_ = ncol >> 6, hd = ncol & 63;
          ((unsigned short*)out)[(((size_t)(b_ * NH + h_) * HDIM + hd) << 11) + s_] = f2b(v);
        } else {
          ((float*)out)[(size_t)mrow * N + ncol] = v;
        }
      }
    }
  }
}

// ---------------- attention with "+1" sink softmax, NO max subtraction ----------------
// Reference computes exp(x)/(1+sum(exp(x))) as written (no max-sub); logits here are
// bounded (|S|<~20 << 88), so P = exp(S) directly is safe in f32/bf16. Row sums ride
// the matrix pipe via a ones-column B-fragment (l accumulates in an MFMA acc).
// Qh: bf16 [B,H,S,HD] pre-scaled by log2(e)/8 (so P = exp2(S) = e^{QK/8});
// Kh: [B,H,S,HD]; Vt: [B,H,HD,S]. X out: bf16 [B,S,D].
// grid (S/128, B*H), 256 threads (4 waves x 32 q-rows). Double-buffered K/V staging.
__global__ __launch_bounds__(256, 3) void k_attn(
    const unsigned short* __restrict__ Qh, const unsigned short* __restrict__ Kh,
    const unsigned short* __restrict__ Vt, unsigned short* __restrict__ X) {
  __shared__ unsigned short Kl[2][64 * 64];  // [kv][hd], chunk-swizzled
  __shared__ unsigned short Vl[2][64 * 64];  // [hd][kv], chunk-swizzled
  __shared__ unsigned short Pl[128 * 64];    // [q][kv],  chunk-swizzled (wave-private rows)

  const int tid = threadIdx.x, wid = tid >> 6, lane = tid & 63;
  const int g = lane >> 4, r16 = lane & 15;
  const int bh = blockIdx.y, b_ = bh >> 4, h_ = bh & 15;
  const int q0 = blockIdx.x * 128;
  const unsigned short* Qp = Qh + ((size_t)bh * SEQ + q0) * HDIM;
  const unsigned short* Kp = Kh + (size_t)bh * SEQ * HDIM;
  const unsigned short* Vp = Vt + (size_t)bh * HDIM * SEQ;
  const int qw = wid * 32;

  // Q fragments for this wave's 32 rows (A-operand: row = lane&15, k = g*8..)
  bf16x8 qf[2][2];
#pragma unroll
  for (int fr = 0; fr < 2; ++fr)
#pragma unroll
    for (int ks = 0; ks < 2; ++ks)
      qf[fr][ks] = *reinterpret_cast<const bf16x8*>(
          Qp + (size_t)(qw + fr * 16 + r16) * HDIM + ks * 32 + g * 8);

  // ones B-fragment: col 0 = 1.0 (bf16 0x3F80) -> D[:,0] = row sums of P
  bf16x8 vones;
#pragma unroll
  for (int i = 0; i < 8; ++i) vones[i] = (r16 == 0) ? (short)0x3F80 : (short)0;

  // staging source/dest offsets (swizzled source chunks; LDS dest wave-linear)
  const int slot0 = wid * 64 + lane, slot1 = (4 + wid) * 64 + lane;
  const int sr0 = slot0 >> 3, sc0 = (slot0 & 7) ^ (sr0 & 7);
  const int sr1 = slot1 >> 3, sc1 = (slot1 & 7) ^ (sr1 & 7);
  const unsigned short* Ks0 = Kp + (size_t)sr0 * HDIM + sc0 * 8;
  const unsigned short* Ks1 = Kp + (size_t)sr1 * HDIM + sc1 * 8;
  const unsigned short* Vs0 = Vp + (size_t)sr0 * SEQ + sc0 * 8;
  const unsigned short* Vs1 = Vp + (size_t)sr1 * SEQ + sc1 * 8;
  const int ld0 = wid * 512, ld1 = (4 + wid) * 512;

  f32x4 o[2][4], ol[2];
#pragma unroll
  for (int fr = 0; fr < 2; ++fr) {
#pragma unroll
    for (int hf = 0; hf < 4; ++hf) o[fr][hf] = f32x4{0.f, 0.f, 0.f, 0.f};
    ol[fr] = f32x4{0.f, 0.f, 0.f, 0.f};
  }

  // prologue: stage tile 0 into buffer 0
  gload16(Ks0, &Kl[0][ld0]);
  gload16(Ks1, &Kl[0][ld1]);
  gload16(Vs0, &Vl[0][ld0]);
  gload16(Vs1, &Vl[0][ld1]);

  int cur = 0;
  for (int t = 0; t < SEQ / 64; ++t) {
    __syncthreads();  // B1: drains vmcnt -> tile t visible
    if (t + 1 < SEQ / 64) {
      const int kv1 = (t + 1) * 64;
      gload16(Ks0 + (size_t)kv1 * HDIM, &Kl[cur ^ 1][ld0]);
      gload16(Ks1 + (size_t)kv1 * HDIM, &Kl[cur ^ 1][ld1]);
      gload16(Vs0 + kv1, &Vl[cur ^ 1][ld0]);
      gload16(Vs1 + kv1, &Vl[cur ^ 1][ld1]);
    }

    // S = Q K^T  (rows = q, cols = kv), S already in log2 units
    f32x4 s_[2][4];
#pragma unroll
    for (int fr = 0; fr < 2; ++fr)
#pragma unroll
      for (int cf = 0; cf < 4; ++cf) s_[fr][cf] = f32x4{0.f, 0.f, 0.f, 0.f};
#pragma unroll
    for (int cf = 0; cf < 4; ++cf) {
      int krow = cf * 16 + r16;
#pragma unroll
      for (int ks = 0; ks < 2; ++ks) {
        bf16x8 kf = *reinterpret_cast<const bf16x8*>(
            &Kl[cur][krow * 64 + (((ks * 4 + g) ^ (krow & 7)) << 3)]);
#pragma unroll
        for (int fr = 0; fr < 2; ++fr)
          s_[fr][cf] = __builtin_amdgcn_mfma_f32_16x16x32_bf16(qf[fr][ks], kf, s_[fr][cf], 0, 0, 0);
      }
    }

    // P = exp2(S) directly (no max subtraction, matching reference numerics); -> LDS bf16
#pragma unroll
    for (int fr = 0; fr < 2; ++fr) {
#pragma unroll
      for (int q = 0; q < 4; ++q) {
        float p0 = ex2(s_[fr][0][q]);
        float p1 = ex2(s_[fr][1][q]);
        float p2 = ex2(s_[fr][2][q]);
        float p3 = ex2(s_[fr][3][q]);
        int prow = qw + fr * 16 + g * 4 + q;
        int base = prow * 64, swz = prow & 7;
        int lo = r16 >> 3, el = r16 & 7;
        Pl[base + (((0 + lo) ^ swz) << 3) + el] = f2b(p0);
        Pl[base + (((2 + lo) ^ swz) << 3) + el] = f2b(p1);
        Pl[base + (((4 + lo) ^ swz) << 3) + el] = f2b(p2);
        Pl[base + (((6 + lo) ^ swz) << 3) + el] = f2b(p3);
      }
    }
    __syncthreads();  // B2: Pl visible

    // O += P V ; l += P 1  (A = P rows q; B = V cols hd from Vt rows / ones col)
#pragma unroll
    for (int ks = 0; ks < 2; ++ks) {
      bf16x8 pf[2];
#pragma unroll
      for (int fr = 0; fr < 2; ++fr) {
        int prow = qw + fr * 16 + r16;
        pf[fr] = *reinterpret_cast<const bf16x8*>(
            &Pl[prow * 64 + (((ks * 4 + g) ^ (prow & 7)) << 3)]);
      }
#pragma unroll
      for (int hf = 0; hf < 4; ++hf) {
        int vrow = hf * 16 + r16;
        bf16x8 vf = *reinterpret_cast<const bf16x8*>(
            &Vl[cur][vrow * 64 + (((ks * 4 + g) ^ (vrow & 7)) << 3)]);
#pragma unroll
        for (int fr = 0; fr < 2; ++fr)
          o[fr][hf] = __builtin_amdgcn_mfma_f32_16x16x32_bf16(pf[fr], vf, o[fr][hf], 0, 0, 0);
      }
#pragma unroll
      for (int fr = 0; fr < 2; ++fr)
        ol[fr] = __builtin_amdgcn_mfma_f32_16x16x32_bf16(pf[fr], vones, ol[fr], 0, 0, 0);
    }
    cur ^= 1;
  }

  // epilogue: l for row 4g+q lives in lane (g,0) reg q; sink adds 1. Write X.
#pragma unroll
  for (int fr = 0; fr < 2; ++fr) {
#pragma unroll
    for (int q = 0; q < 4; ++q) {
      float lsum = __shfl(ol[fr][q], lane & 48, 64);
      float inv = 1.0f / (1.0f + lsum);
      int row = q0 + qw + fr * 16 + g * 4 + q;
      unsigned short* xp = X + (size_t)(b_ * SEQ + row) * DIM + h_ * 64;
#pragma unroll
      for (int hf = 0; hf < 4; ++hf) xp[hf * 16 + r16] = f2b(o[fr][hf][q] * inv);
    }
  }
}

extern "C" void kernel_launch(void* const* d_in, const int* in_sizes, int n_in,
                              void* d_out, int out_size, void* d_ws, size_t ws_size,
                              hipStream_t stream) {
  const float* q  = (const float*)d_in[0];
  const float* k  = (const float*)d_in[1];
  const float* v  = (const float*)d_in[2];
  const float* Wq = (const float*)d_in[3];
  const float* bq = (const float*)d_in[4];
  const float* Wk = (const float*)d_in[5];
  const float* bk = (const float*)d_in[6];
  const float* Wv = (const float*)d_in[7];
  const float* bv = (const float*)d_in[8];
  const float* Wf = (const float*)d_in[9];
  const float* bf = (const float*)d_in[10];

  char* ws = (char*)d_ws;
  unsigned short* Abuf = (unsigned short*)ws;                              // 8192*1024 bf16 (also attn X)
  unsigned short* Wt   = (unsigned short*)(ws + (size_t)16777216);         // up to 1024*1024 bf16
  unsigned short* Qh   = (unsigned short*)(ws + (size_t)16777216 + 2097152);
  unsigned short* Kh   = Qh + (size_t)MROWS * DIM;
  unsigned short* Vtb  = Kh + (size_t)MROWS * DIM;

  dim3 cvtg(4096), b256(256);
  dim3 tb(32, 8);
  dim3 gemmg(64, 8);
  dim3 attng(16, 64);
  dim3 fing(64, 2);

  const int n8 = MROWS * DIM / 8;
  const float qscale = 0.125f * 1.44269504088896f;  // 1/sqrt(64) * log2(e): S in log2 units

  // Q path
  k_cvt<<<cvtg, b256, 0, stream>>>(q, Abuf, n8);
  k_tcvt<<<dim3(32, 32), tb, 0, stream>>>(Wq, Wt, DIM, DIM);
  k_gemm<0><<<gemmg, b256, 0, stream>>>(Abuf, Wt, bq, (void*)Qh, DIM, DIM, qscale);
  // K path
  k_cvt<<<cvtg, b256, 0, stream>>>(k, Abuf, n8);
  k_tcvt<<<dim3(32, 32), tb, 0, stream>>>(Wk, Wt, DIM, DIM);
  k_gemm<0><<<gemmg, b256, 0, stream>>>(Abuf, Wt, bk, (void*)Kh, DIM, DIM, 1.0f);
  // V path (stored transposed per head)
  k_cvt<<<cvtg, b256, 0, stream>>>(v, Abuf, n8);
  k_tcvt<<<dim3(32, 32), tb, 0, stream>>>(Wv, Wt, DIM, DIM);
  k_gemm<1><<<gemmg, b256, 0, stream>>>(Abuf, Wt, bv, (void*)Vtb, DIM, DIM, 1.0f);
  // attention -> X (reuse Abuf)
  k_attn<<<attng, b256, 0, stream>>>(Qh, Kh, Vtb, Abuf);
  // final projection -> f32 out
  k_tcvt<<<dim3(8, 32), tb, 0, stream>>>(Wf, Wt, DIM, DOUT);
  k_gemm<2><<<fing, b256, 0, stream>>>(Abuf, Wt, bf, d_out, DIM, DOUT, 1.0f);
}

// Round 8
// 248.549 us; speedup vs baseline: 1.5140x; 1.0133x over previous
//
#include <hip/hip_runtime.h>
#include <stdint.h>

#define DI __device__ __forceinline__

typedef __attribute__((ext_vector_type(8))) short bf16x8;
typedef __attribute__((ext_vector_type(4))) float f32x4;
typedef __attribute__((ext_vector_type(8))) unsigned short u16x8;

static constexpr int BATCH = 4, SEQ = 2048, DIM = 1024, NH = 16, HDIM = 64, DOUT = 256;
static constexpr int MROWS = BATCH * SEQ;  // 8192

DI unsigned short f2b(float f) {
  union { float f; unsigned u; } v; v.f = f;
  unsigned u = v.u + 0x7FFFu + ((v.u >> 16) & 1u);
  return (unsigned short)(u >> 16);
}

DI float ex2(float x) {  // 2^x, single v_exp_f32
#if __has_builtin(__builtin_amdgcn_exp2f)
  return __builtin_amdgcn_exp2f(x);
#else
  float r; asm("v_exp_f32 %0, %1" : "=v"(r) : "v"(x)); return r;
#endif
}

typedef const __attribute__((address_space(1))) unsigned int* gp1;
typedef __attribute__((address_space(3))) unsigned int* lp3;
DI void gload16(const void* g, void* l) {
  __builtin_amdgcn_global_load_lds((gp1)g, (lp3)l, 16, 0, 0);
}

// ---------------- f32 -> bf16 convert (8 elems/thread) ----------------
__global__ void k_cvt(const float* __restrict__ s, unsigned short* __restrict__ d, int n8) {
  int i = blockIdx.x * 256 + threadIdx.x;
  if (i >= n8) return;
  const float4* sp = reinterpret_cast<const float4*>(s) + (size_t)i * 2;
  float4 a = sp[0], b = sp[1];
  u16x8 r;
  r[0] = f2b(a.x); r[1] = f2b(a.y); r[2] = f2b(a.z); r[3] = f2b(a.w);
  r[4] = f2b(b.x); r[5] = f2b(b.y); r[6] = f2b(b.z); r[7] = f2b(b.w);
  *reinterpret_cast<u16x8*>(d + (size_t)i * 8) = r;
}

// ---------------- f32 [R][C] -> bf16 [C][R] transpose-convert ----------------
__global__ void k_tcvt(const float* __restrict__ s, unsigned short* __restrict__ d, int R, int C) {
  __shared__ float t[32][33];
  int c0 = blockIdx.x * 32, r0 = blockIdx.y * 32;
  int tx = threadIdx.x, ty = threadIdx.y;  // block (32,8)
#pragma unroll
  for (int j = 0; j < 32; j += 8)
    t[ty + j][tx] = s[(size_t)(r0 + ty + j) * C + c0 + tx];
  __syncthreads();
#pragma unroll
  for (int j = 0; j < 32; j += 8)
    d[(size_t)(c0 + ty + j) * R + r0 + tx] = f2b(t[tx][ty + j]);
}

// ---------------- bf16 GEMM: A[M,K] x Bt[N,K]^T, 128x128 tile, BK=32 ----------------
// MODE 0: out bf16 [B,H,S,HD]   (n = h*64+hd, m = b*2048+s), v = (acc+bias)*scale
// MODE 1: out bf16 [B,H,HD,S]   (V transposed per head)
// MODE 2: out f32  [M,N] row-major
template <int MODE>
__global__ __launch_bounds__(256, 2) void k_gemm(
    const unsigned short* __restrict__ A, const unsigned short* __restrict__ Bt,
    const float* __restrict__ bias, void* __restrict__ out, int K, int N, float scale) {
  __shared__ unsigned short Al[128 * 32];
  __shared__ unsigned short Bl[128 * 32];
  const int tid = threadIdx.x, wid = tid >> 6, lane = tid & 63;
  const int m0 = blockIdx.x * 128, n0 = blockIdx.y * 128;
  const int wr = wid >> 1, wc = wid & 1;
  const int g = lane >> 4, r16 = lane & 15;

  f32x4 acc[4][4];
#pragma unroll
  for (int i = 0; i < 4; ++i)
#pragma unroll
    for (int j = 0; j < 4; ++j) acc[i][j] = f32x4{0.f, 0.f, 0.f, 0.f};

  for (int kk = 0; kk < K; kk += 32) {
#pragma unroll
    for (int is = 0; is < 2; ++is) {
      int slot = (is * 4 + wid) * 64 + lane;
      int row = slot >> 2, ch = slot & 3;
      gload16(A + (size_t)(m0 + row) * K + kk + ch * 8, &Al[(is * 4 + wid) * 64 * 8]);
    }
#pragma unroll
    for (int is = 0; is < 2; ++is) {
      int slot = (is * 4 + wid) * 64 + lane;
      int row = slot >> 2, ch = slot & 3;
      gload16(Bt + (size_t)(n0 + row) * K + kk + ch * 8, &Bl[(is * 4 + wid) * 64 * 8]);
    }
    __syncthreads();
    bf16x8 af[4], bfv[4];
#pragma unroll
    for (int i = 0; i < 4; ++i)
      af[i] = *reinterpret_cast<const bf16x8*>(&Al[(wr * 64 + i * 16 + r16) * 32 + g * 8]);
#pragma unroll
    for (int j = 0; j < 4; ++j)
      bfv[j] = *reinterpret_cast<const bf16x8*>(&Bl[(wc * 64 + j * 16 + r16) * 32 + g * 8]);
#pragma unroll
    for (int i = 0; i < 4; ++i)
#pragma unroll
      for (int j = 0; j < 4; ++j)
        acc[i][j] = __builtin_amdgcn_mfma_f32_16x16x32_bf16(af[i], bfv[j], acc[i][j], 0, 0, 0);
    __syncthreads();
  }

  const int rr = g * 4;
#pragma unroll
  for (int i = 0; i < 4; ++i) {
#pragma unroll
    for (int j = 0; j < 4; ++j) {
#pragma unroll
      for (int q = 0; q < 4; ++q) {
        int mrow = m0 + wr * 64 + i * 16 + rr + q;
        int ncol = n0 + wc * 64 + j * 16 + r16;
        float v = (acc[i][j][q] + bias[ncol]) * scale;
        if (MODE == 0) {
          int b_ = mrow >> 11, s_ = mrow & 2047;
          int h_ = ncol >> 6, hd = ncol & 63;
          ((unsigned short*)out)[(((size_t)(b_ * NH + h_) * SEQ + s_) << 6) + hd] = f2b(v);
        } else if (MODE == 1) {
          int b_ = mrow >> 11, s_ = mrow & 2047;
          int h_ = ncol >> 6, hd = ncol & 63;
          ((unsigned short*)out)[(((size_t)(b_ * NH + h_) * HDIM + hd) << 11) + s_] = f2b(v);
        } else {
          ((float*)out)[(size_t)mrow * N + ncol] = v;
        }
      }
    }
  }
}

// ---------------- attention with "+1" sink softmax, NO max subtraction ----------------
// P = exp2(S) directly (reference computes exp(x)/(1+sum) without max-sub; logits
// bounded). Row sums ride the matrix pipe via a ones-column B-fragment.
// B2 barrier REMOVED: Pl rows are wave-private (wave wid owns rows [wid*32,wid*32+32)),
// so the P write->read RAW is same-wave and ordered by compiler lgkmcnt waits; only
// the cross-wave K/V staging needs the B1 __syncthreads. Waves now drift within a
// tile: one wave's exp/stores overlap another's PV MFMAs.
__global__ __launch_bounds__(256, 3) void k_attn(
    const unsigned short* __restrict__ Qh, const unsigned short* __restrict__ Kh,
    const unsigned short* __restrict__ Vt, unsigned short* __restrict__ X) {
  __shared__ unsigned short Kl[2][64 * 64];  // [kv][hd], chunk-swizzled
  __shared__ unsigned short Vl[2][64 * 64];  // [hd][kv], chunk-swizzled
  __shared__ unsigned short Pl[128 * 64];    // [q][kv],  chunk-swizzled (wave-private rows)

  const int tid = threadIdx.x, wid = tid >> 6, lane = tid & 63;
  const int g = lane >> 4, r16 = lane & 15;
  const int bh = blockIdx.y, b_ = bh >> 4, h_ = bh & 15;
  const int q0 = blockIdx.x * 128;
  const unsigned short* Qp = Qh + ((size_t)bh * SEQ + q0) * HDIM;
  const unsigned short* Kp = Kh + (size_t)bh * SEQ * HDIM;
  const unsigned short* Vp = Vt + (size_t)bh * HDIM * SEQ;
  const int qw = wid * 32;

  // Q fragments for this wave's 32 rows (A-operand: row = lane&15, k = g*8..)
  bf16x8 qf[2][2];
#pragma unroll
  for (int fr = 0; fr < 2; ++fr)
#pragma unroll
    for (int ks = 0; ks < 2; ++ks)
      qf[fr][ks] = *reinterpret_cast<const bf16x8*>(
          Qp + (size_t)(qw + fr * 16 + r16) * HDIM + ks * 32 + g * 8);

  // ones B-fragment: col 0 = 1.0 (bf16 0x3F80) -> D[:,0] = row sums of P
  bf16x8 vones;
#pragma unroll
  for (int i = 0; i < 8; ++i) vones[i] = (r16 == 0) ? (short)0x3F80 : (short)0;

  // staging source/dest offsets (swizzled source chunks; LDS dest wave-linear)
  const int slot0 = wid * 64 + lane, slot1 = (4 + wid) * 64 + lane;
  const int sr0 = slot0 >> 3, sc0 = (slot0 & 7) ^ (sr0 & 7);
  const int sr1 = slot1 >> 3, sc1 = (slot1 & 7) ^ (sr1 & 7);
  const unsigned short* Ks0 = Kp + (size_t)sr0 * HDIM + sc0 * 8;
  const unsigned short* Ks1 = Kp + (size_t)sr1 * HDIM + sc1 * 8;
  const unsigned short* Vs0 = Vp + (size_t)sr0 * SEQ + sc0 * 8;
  const unsigned short* Vs1 = Vp + (size_t)sr1 * SEQ + sc1 * 8;
  const int ld0 = wid * 512, ld1 = (4 + wid) * 512;

  f32x4 o[2][4], ol[2];
#pragma unroll
  for (int fr = 0; fr < 2; ++fr) {
#pragma unroll
    for (int hf = 0; hf < 4; ++hf) o[fr][hf] = f32x4{0.f, 0.f, 0.f, 0.f};
    ol[fr] = f32x4{0.f, 0.f, 0.f, 0.f};
  }

  // prologue: stage tile 0 into buffer 0
  gload16(Ks0, &Kl[0][ld0]);
  gload16(Ks1, &Kl[0][ld1]);
  gload16(Vs0, &Vl[0][ld0]);
  gload16(Vs1, &Vl[0][ld1]);

  int cur = 0;
  for (int t = 0; t < SEQ / 64; ++t) {
    __syncthreads();  // B1: drains vmcnt -> tile t visible; orders prev PV reads vs next STAGE
    if (t + 1 < SEQ / 64) {
      const int kv1 = (t + 1) * 64;
      gload16(Ks0 + (size_t)kv1 * HDIM, &Kl[cur ^ 1][ld0]);
      gload16(Ks1 + (size_t)kv1 * HDIM, &Kl[cur ^ 1][ld1]);
      gload16(Vs0 + kv1, &Vl[cur ^ 1][ld0]);
      gload16(Vs1 + kv1, &Vl[cur ^ 1][ld1]);
    }

    // S = Q K^T  (rows = q, cols = kv), S already in log2 units
    f32x4 s_[2][4];
#pragma unroll
    for (int fr = 0; fr < 2; ++fr)
#pragma unroll
      for (int cf = 0; cf < 4; ++cf) s_[fr][cf] = f32x4{0.f, 0.f, 0.f, 0.f};
#pragma unroll
    for (int cf = 0; cf < 4; ++cf) {
      int krow = cf * 16 + r16;
#pragma unroll
      for (int ks = 0; ks < 2; ++ks) {
        bf16x8 kf = *reinterpret_cast<const bf16x8*>(
            &Kl[cur][krow * 64 + (((ks * 4 + g) ^ (krow & 7)) << 3)]);
#pragma unroll
        for (int fr = 0; fr < 2; ++fr)
          s_[fr][cf] = __builtin_amdgcn_mfma_f32_16x16x32_bf16(qf[fr][ks], kf, s_[fr][cf], 0, 0, 0);
      }
    }

    // P = exp2(S) (no max subtraction, matching reference numerics); -> LDS bf16
#pragma unroll
    for (int fr = 0; fr < 2; ++fr) {
#pragma unroll
      for (int q = 0; q < 4; ++q) {
        float p0 = ex2(s_[fr][0][q]);
        float p1 = ex2(s_[fr][1][q]);
        float p2 = ex2(s_[fr][2][q]);
        float p3 = ex2(s_[fr][3][q]);
        int prow = qw + fr * 16 + g * 4 + q;
        int base = prow * 64, swz = prow & 7;
        int lo = r16 >> 3, el = r16 & 7;
        Pl[base + (((0 + lo) ^ swz) << 3) + el] = f2b(p0);
        Pl[base + (((2 + lo) ^ swz) << 3) + el] = f2b(p1);
        Pl[base + (((4 + lo) ^ swz) << 3) + el] = f2b(p2);
        Pl[base + (((6 + lo) ^ swz) << 3) + el] = f2b(p3);
      }
    }
    // (no barrier: Pl rows are wave-private; same-wave LDS RAW is hardware/compiler ordered)

    // O += P V ; l += P 1  (A = P rows q; B = V cols hd from Vt rows / ones col)
#pragma unroll
    for (int ks = 0; ks < 2; ++ks) {
      bf16x8 pf[2];
#pragma unroll
      for (int fr = 0; fr < 2; ++fr) {
        int prow = qw + fr * 16 + r16;
        pf[fr] = *reinterpret_cast<const bf16x8*>(
            &Pl[prow * 64 + (((ks * 4 + g) ^ (prow & 7)) << 3)]);
      }
#pragma unroll
      for (int hf = 0; hf < 4; ++hf) {
        int vrow = hf * 16 + r16;
        bf16x8 vf = *reinterpret_cast<const bf16x8*>(
            &Vl[cur][vrow * 64 + (((ks * 4 + g) ^ (vrow & 7)) << 3)]);
#pragma unroll
        for (int fr = 0; fr < 2; ++fr)
          o[fr][hf] = __builtin_amdgcn_mfma_f32_16x16x32_bf16(pf[fr], vf, o[fr][hf], 0, 0, 0);
      }
#pragma unroll
      for (int fr = 0; fr < 2; ++fr)
        ol[fr] = __builtin_amdgcn_mfma_f32_16x16x32_bf16(pf[fr], vones, ol[fr], 0, 0, 0);
    }
    cur ^= 1;
  }

  // epilogue: l for row 4g+q lives in lane (g,0) reg q; sink adds 1. Write X.
#pragma unroll
  for (int fr = 0; fr < 2; ++fr) {
#pragma unroll
    for (int q = 0; q < 4; ++q) {
      float lsum = __shfl(ol[fr][q], lane & 48, 64);
      float inv = 1.0f / (1.0f + lsum);
      int row = q0 + qw + fr * 16 + g * 4 + q;
      unsigned short* xp = X + (size_t)(b_ * SEQ + row) * DIM + h_ * 64;
#pragma unroll
      for (int hf = 0; hf < 4; ++hf) xp[hf * 16 + r16] = f2b(o[fr][hf][q] * inv);
    }
  }
}

extern "C" void kernel_launch(void* const* d_in, const int* in_sizes, int n_in,
                              void* d_out, int out_size, void* d_ws, size_t ws_size,
                              hipStream_t stream) {
  const float* q  = (const float*)d_in[0];
  const float* k  = (const float*)d_in[1];
  const float* v  = (const float*)d_in[2];
  const float* Wq = (const float*)d_in[3];
  const float* bq = (const float*)d_in[4];
  const float* Wk = (const float*)d_in[5];
  const float* bk = (const float*)d_in[6];
  const float* Wv = (const float*)d_in[7];
  const float* bv = (const float*)d_in[8];
  const float* Wf = (const float*)d_in[9];
  const float* bf = (const float*)d_in[10];

  char* ws = (char*)d_ws;
  unsigned short* Abuf = (unsigned short*)ws;                              // 8192*1024 bf16 (also attn X)
  unsigned short* Wt   = (unsigned short*)(ws + (size_t)16777216);         // up to 1024*1024 bf16
  unsigned short* Qh   = (unsigned short*)(ws + (size_t)16777216 + 2097152);
  unsigned short* Kh   = Qh + (size_t)MROWS * DIM;
  unsigned short* Vtb  = Kh + (size_t)MROWS * DIM;

  dim3 cvtg(4096), b256(256);
  dim3 tb(32, 8);
  dim3 gemmg(64, 8);
  dim3 attng(16, 64);
  dim3 fing(64, 2);

  const int n8 = MROWS * DIM / 8;
  const float qscale = 0.125f * 1.44269504088896f;  // 1/sqrt(64) * log2(e): S in log2 units

  // Q path
  k_cvt<<<cvtg, b256, 0, stream>>>(q, Abuf, n8);
  k_tcvt<<<dim3(32, 32), tb, 0, stream>>>(Wq, Wt, DIM, DIM);
  k_gemm<0><<<gemmg, b256, 0, stream>>>(Abuf, Wt, bq, (void*)Qh, DIM, DIM, qscale);
  // K path
  k_cvt<<<cvtg, b256, 0, stream>>>(k, Abuf, n8);
  k_tcvt<<<dim3(32, 32), tb, 0, stream>>>(Wk, Wt, DIM, DIM);
  k_gemm<0><<<gemmg, b256, 0, stream>>>(Abuf, Wt, bk, (void*)Kh, DIM, DIM, 1.0f);
  // V path (stored transposed per head)
  k_cvt<<<cvtg, b256, 0, stream>>>(v, Abuf, n8);
  k_tcvt<<<dim3(32, 32), tb, 0, stream>>>(Wv, Wt, DIM, DIM);
  k_gemm<1><<<gemmg, b256, 0, stream>>>(Abuf, Wt, bv, (void*)Vtb, DIM, DIM, 1.0f);
  // attention -> X (reuse Abuf)
  k_attn<<<attng, b256, 0, stream>>>(Qh, Kh, Vtb, Abuf);
  // final projection -> f32 out
  k_tcvt<<<dim3(8, 32), tb, 0, stream>>>(Wf, Wt, DIM, DOUT);
  k_gemm<2><<<fing, b256, 0, stream>>>(Abuf, Wt, bf, d_out, DIM, DOUT, 1.0f);
}